// Round 5
// baseline (2352.996 us; speedup 1.0000x reference)
//
#include <hip/hip_runtime.h>
#include <math.h>

#define E_CNT 800000
#define G_CNT 1000000
#define NUM_NODES 100000
#define NT (G_CNT / 32)        // 31250 tiles of 32 groups
#define GRID 512               // persistent blocks (2 per CU)
#define TPB 512                // 8 waves

typedef __attribute__((ext_vector_type(8))) short bf16x8;    // 8 bf16 = 4 VGPRs
typedef __attribute__((ext_vector_type(16))) float f32x16;

__device__ __forceinline__ short f2bf(float f) {
    union { float f; unsigned u; } v; v.f = f;
    unsigned r = v.u + 0x7fffu + ((v.u >> 16) & 1u);   // RNE
    return (short)(r >> 16);
}

__global__ void zero_deg_kernel(float* __restrict__ deg) {
    int i = blockIdx.x * blockDim.x + threadIdx.x;
    if (i < NUM_NODES) deg[i] = 0.0f;
}

__global__ void degree_kernel(const int* __restrict__ ei, float* __restrict__ deg) {
    int e = blockIdx.x * blockDim.x + threadIdx.x;
    if (e < E_CNT) {
        atomicAdd(&deg[ei[e]], 1.0f);
        atomicAdd(&deg[ei[E_CNT + e]], 1.0f);
    }
}

// W1T[n][k] = bf16(W1[k][n])
__global__ void prep_w1t_kernel(const float* __restrict__ W1, short* __restrict__ w1t) {
    int t = blockIdx.x * blockDim.x + threadIdx.x;   // 65536
    int n = t >> 8, k = t & 255;
    w1t[t] = f2bf(W1[k * 256 + n]);
}

// emb fp32 (800000x128) -> bf16 copy
__global__ void prep_emb_kernel(const float* __restrict__ emb, short* __restrict__ ebf) {
    long t = (long)blockIdx.x * blockDim.x + threadIdx.x;
    const float4* e4 = (const float4*)emb;
    float4 v0 = e4[t * 2], v1 = e4[t * 2 + 1];
    bf16x8 h;
    h[0] = f2bf(v0.x); h[1] = f2bf(v0.y); h[2] = f2bf(v0.z); h[3] = f2bf(v0.w);
    h[4] = f2bf(v1.x); h[5] = f2bf(v1.y); h[6] = f2bf(v1.z); h[7] = f2bf(v1.w);
    *(bf16x8*)&ebf[t * 8] = h;
}

// Persistent-block kernel. MODE 2: gather bf16 table; MODE 1: gather fp32 emb.
// pairS swizzle: 16B chunk c of row r holds logical chunk (c ^ (r&7)).
template <int MODE>
__launch_bounds__(TPB, 4)
__global__ void egis_main_kernel(
    const float* __restrict__ emb,
    const int*   __restrict__ eg,
    const int*   __restrict__ ei,
    const float* __restrict__ b1,
    const float* __restrict__ W2, const float* __restrict__ b2,
    const float* __restrict__ Ws1, const float* __restrict__ bs1,
    const float* __restrict__ Ws2, const float* __restrict__ bs2,
    const float* __restrict__ Wc1, const float* __restrict__ bc1,
    const float* __restrict__ Wc2, const float* __restrict__ bc2,
    const float* __restrict__ deg,
    const short* __restrict__ w1t,   // (256,256) bf16 [n][k]
    const short* __restrict__ ebf,   // (E,128) bf16
    float* __restrict__ out)
{
    __shared__ short pairS[2][32][256];   // 32 KB double-buffered; holds pair, then relu(h)
    __shared__ short w2tS[8][264];        // W2^T bf16 (row n, k-stride 264)
    __shared__ float compS[32][8];
    __shared__ float sfS[32][4];
    __shared__ int   gS[2][2][32];        // [buf][g0/g1][row]

    const int tid = threadIdx.x;
    const int wv = tid >> 6, lane = tid & 63;
    const int l32 = lane & 31, lh32 = lane >> 5;
    const int axr = l32 & 7;

    // ---- one-time setup: W1T fragments into registers, W2 into LDS ----
    bf16x8 bReg[16];
    {
        const bf16x8* B8 = (const bf16x8*)w1t;       // 32 chunks per n-row
        const int bBase = (wv * 32 + l32) * 32 + lh32;
        #pragma unroll
        for (int ks = 0; ks < 16; ++ks) bReg[ks] = B8[bBase + ks * 2];
    }
    const float b1v = b1[wv * 32 + l32];
    #pragma unroll
    for (int it = 0; it < 4; ++it) {
        int idx = it * TPB + tid;                    // k*8+n
        w2tS[idx & 7][idx >> 3] = f2bf(W2[idx]);
    }

    // ---- prologue: indices + gather for first tile; eg prefetch for second ----
    int t = blockIdx.x;
    if (tid < 32) {
        int2 g = ((const int2*)eg)[t * 32 + tid];
        gS[0][0][tid] = g.x; gS[0][1][tid] = g.y;
    }
    __syncthreads();

    bf16x8 gReg[2];
    float4 gRegF[2][2];
    #pragma unroll
    for (int it = 0; it < 2; ++it) {
        int idx = it * TPB + tid;                    // row*32 + chunk
        int r = idx >> 5, rc = idx & 31;
        int gi = rc ^ (r & 7);
        int grow = (gi & 16) ? gS[0][1][r] : gS[0][0][r];
        if constexpr (MODE == 2) {
            gReg[it] = *(const bf16x8*)(ebf + (long)grow * 128 + (gi & 15) * 8);
        } else {
            const float4* s4 = (const float4*)(emb + (long)grow * 128 + (gi & 15) * 8);
            gRegF[it][0] = s4[0]; gRegF[it][1] = s4[1];
        }
    }
    int2 egReg = {0, 0};
    {
        int tn = (t + GRID < NT) ? t + GRID : NT - 1;
        if (tid < 32) egReg = ((const int2*)eg)[tn * 32 + tid];
    }

    int cur = 0;
    while (t < NT) {
        const int nxt = cur ^ 1;
        const int tNext = t + GRID;

        // issue eg prefetch two tiles ahead
        int2 egNext2 = {0, 0};
        {
            int tn2 = (t + 2 * GRID < NT) ? t + 2 * GRID : NT - 1;
            if (tid < 32) egNext2 = ((const int2*)eg)[tn2 * 32 + tid];
        }

        // write gathered pair(t) into pairS[cur]
        #pragma unroll
        for (int it = 0; it < 2; ++it) {
            int idx = it * TPB + tid;
            int r = idx >> 5, rc = idx & 31;
            if constexpr (MODE == 2) {
                *(bf16x8*)&pairS[cur][r][rc * 8] = gReg[it];
            } else {
                float4 v0 = gRegF[it][0], v1 = gRegF[it][1];
                bf16x8 h;
                h[0] = f2bf(v0.x); h[1] = f2bf(v0.y); h[2] = f2bf(v0.z); h[3] = f2bf(v0.w);
                h[4] = f2bf(v1.x); h[5] = f2bf(v1.y); h[6] = f2bf(v1.z); h[7] = f2bf(v1.w);
                *(bf16x8*)&pairS[cur][r][rc * 8] = h;
            }
        }
        if (tid < 32) { gS[nxt][0][tid] = egReg.x; gS[nxt][1][tid] = egReg.y; }
        __syncthreads();   // pairS[cur] + gS[nxt] visible

        // issue gather(t+GRID) into gReg (consumed next iteration)
        #pragma unroll
        for (int it = 0; it < 2; ++it) {
            int idx = it * TPB + tid;
            int r = idx >> 5, rc = idx & 31;
            int gi = rc ^ (r & 7);
            int grow = (gi & 16) ? gS[nxt][1][r] : gS[nxt][0][r];
            if constexpr (MODE == 2) {
                gReg[it] = *(const bf16x8*)(ebf + (long)grow * 128 + (gi & 15) * 8);
            } else {
                const float4* s4 = (const float4*)(emb + (long)grow * 128 + (gi & 15) * 8);
                gRegF[it][0] = s4[0]; gRegF[it][1] = s4[1];
            }
        }

        // issue ss first-level random loads for tile t
        int eiv = 0;
        if (tid < 128) {
            int r = tid >> 2, j = tid & 3;
            int node = (j < 2) ? gS[cur][0][r] : gS[cur][1][r];
            eiv = ei[(j & 1) * E_CNT + node];
        }

        // ---- hidden = relu(pair @ W1 + b1): one 32x32 C-tile per wave ----
        f32x16 acc;
        #pragma unroll
        for (int i = 0; i < 16; ++i) acc[i] = b1v;
        {
            const short* aRow = &pairS[cur][l32][0];
            #pragma unroll
            for (int ks = 0; ks < 16; ++ks) {
                bf16x8 a = *(const bf16x8*)(aRow + (((ks * 2 + lh32) ^ axr)) * 8);
                acc = __builtin_amdgcn_mfma_f32_32x32x16_bf16(a, bReg[ks], acc, 0, 0, 0);
            }
        }
        __syncthreads();   // all waves done reading pairS[cur]

        // store relu(h) bf16 back into pairS[cur] (same swizzle)
        #pragma unroll
        for (int g = 0; g < 4; ++g) {
            #pragma unroll
            for (int i = 0; i < 4; ++i) {
                int row = g * 8 + lh32 * 4 + i;        // D: row=(reg&3)+8*(reg>>2)+4*(lane>>5)
                int col = wv * 32 + l32;               //    col=lane&31
                pairS[cur][row][col ^ ((row & 7) << 3)] = f2bf(fmaxf(acc[g * 4 + i], 0.f));
            }
        }

        // consume ei, issue deg loads
        float degv = 0.f;
        if (tid < 128) degv = deg[eiv];
        __syncthreads();   // h tile visible

        if (tid < 128) {
            int r = tid >> 2, j = tid & 3;
            sfS[r][j] = degv;
        }
        // ---- comp = relu(h @ W2 + b2): wave 0 only, cols 8..31 junk-masked ----
        if (wv == 0) {
            float c0 = (l32 < 8) ? b2[l32] : 0.f;
            f32x16 a2;
            #pragma unroll
            for (int i = 0; i < 16; ++i) a2[i] = c0;
            const short* hRow = &pairS[cur][l32][0];
            const short* w2row = &w2tS[l32 & 7][0];
            #pragma unroll
            for (int ks = 0; ks < 16; ++ks) {
                bf16x8 a = *(const bf16x8*)(hRow + (((ks * 2 + lh32) ^ axr)) * 8);
                bf16x8 b = *(const bf16x8*)(w2row + (ks * 2 + lh32) * 8);
                a2 = __builtin_amdgcn_mfma_f32_32x32x16_bf16(a, b, a2, 0, 0, 0);
            }
            if (l32 < 8) {
                #pragma unroll
                for (int g = 0; g < 4; ++g)
                    #pragma unroll
                    for (int i = 0; i < 4; ++i)
                        compS[g * 8 + lh32 * 4 + i][l32] = fmaxf(a2[g * 4 + i], 0.f);
            }
        }
        __syncthreads();   // compS + sfS visible

        // ---- tail: ss + head MLP, 16 threads per group-row ----
        {
            int r = tid >> 4, q = tid & 15;
            float s0 = sfS[r][0], s1 = sfS[r][1], s2 = sfS[r][2], s3 = sfS[r][3];
            float part = 0.f;
            #pragma unroll
            for (int i = 0; i < 4; ++i) {
                int u = q * 4 + i;
                float h = bs1[u] + s0 * Ws1[u] + s1 * Ws1[64 + u]
                                 + s2 * Ws1[128 + u] + s3 * Ws1[192 + u];
                part += fmaxf(h, 0.f) * Ws2[u];
            }
            part += __shfl_xor(part, 1);
            part += __shfl_xor(part, 2);
            part += __shfl_xor(part, 4);
            part += __shfl_xor(part, 8);
            float ssv = part + bs2[0];

            float as[8];
            #pragma unroll
            for (int a = 0; a < 8; ++a) as[a] = compS[r][a];
            float p2 = 0.f;
            #pragma unroll
            for (int i = 0; i < 8; ++i) {
                int u = q * 8 + i;
                float h = bc1[u];
                #pragma unroll
                for (int a = 0; a < 8; ++a) h += as[a] * Wc1[a * 128 + u];
                h += ssv * Wc1[1024 + u];
                p2 += fmaxf(h, 0.f) * Wc2[u];
            }
            p2 += __shfl_xor(p2, 1);
            p2 += __shfl_xor(p2, 2);
            p2 += __shfl_xor(p2, 4);
            p2 += __shfl_xor(p2, 8);
            if (q == 0) out[t * 32 + r] = 1.f / (1.f + expf(-(p2 + bc2[0])));
        }

        egReg = egNext2;
        cur = nxt;
        t = tNext;
    }
}

extern "C" void kernel_launch(void* const* d_in, const int* in_sizes, int n_in,
                              void* d_out, int out_size, void* d_ws, size_t ws_size,
                              hipStream_t stream) {
    const float* emb = (const float*)d_in[0];
    const int*   eg  = (const int*)d_in[1];
    const int*   ei  = (const int*)d_in[2];
    const float* W1  = (const float*)d_in[3];
    const float* b1  = (const float*)d_in[4];
    const float* W2  = (const float*)d_in[5];
    const float* b2  = (const float*)d_in[6];
    const float* Ws1 = (const float*)d_in[7];
    const float* bs1 = (const float*)d_in[8];
    const float* Ws2 = (const float*)d_in[9];
    const float* bs2 = (const float*)d_in[10];
    const float* Wc1 = (const float*)d_in[11];
    const float* bc1 = (const float*)d_in[12];
    const float* Wc2 = (const float*)d_in[13];
    const float* bc2 = (const float*)d_in[14];
    float* out = (float*)d_out;

    // ws: deg | w1t bf16 | ebf bf16
    float* deg = (float*)d_ws;
    size_t degB = ((size_t)NUM_NODES * 4 + 255) & ~(size_t)255;
    short* w1t = (short*)((char*)d_ws + degB);
    size_t w1tB = 256 * 256 * sizeof(short);
    short* ebf = (short*)((char*)d_ws + degB + w1tB);
    size_t embB = (size_t)E_CNT * 128 * sizeof(short);

    int mode = (ws_size >= degB + w1tB + embB) ? 2 : 1;

    zero_deg_kernel<<<(NUM_NODES + 255) / 256, 256, 0, stream>>>(deg);
    degree_kernel<<<(E_CNT + 255) / 256, 256, 0, stream>>>(ei, deg);
    prep_w1t_kernel<<<65536 / 256, 256, 0, stream>>>(W1, w1t);
    if (mode == 2) {
        prep_emb_kernel<<<50000, 256, 0, stream>>>(emb, ebf);
        egis_main_kernel<2><<<GRID, TPB, 0, stream>>>(
            emb, eg, ei, b1, W2, b2, Ws1, bs1, Ws2, bs2, Wc1, bc1, Wc2, bc2,
            deg, w1t, ebf, out);
    } else {
        egis_main_kernel<1><<<GRID, TPB, 0, stream>>>(
            emb, eg, ei, b1, W2, b2, Ws1, bs1, Ws2, bs2, Wc1, bc1, Wc2, bc2,
            deg, w1t, (const short*)nullptr, out);
    }
}

// Round 6
// 956.668 us; speedup vs baseline: 2.4596x; 2.4596x over previous
//
#include <hip/hip_runtime.h>
#include <math.h>

#define E_CNT 800000
#define G_CNT 1000000
#define NUM_NODES 100000
#define NT (G_CNT / 32)        // 31250 tiles of 32 groups
#define GRID 256               // persistent blocks (1 per CU)
#define TPB 512                // 8 waves

typedef __attribute__((ext_vector_type(8))) short bf16x8;    // 8 bf16 = 4 VGPRs
typedef __attribute__((ext_vector_type(16))) float f32x16;

__device__ __forceinline__ short f2bf(float f) {
    union { float f; unsigned u; } v; v.f = f;
    unsigned r = v.u + 0x7fffu + ((v.u >> 16) & 1u);   // RNE
    return (short)(r >> 16);
}

__global__ void zero_deg_kernel(float* __restrict__ deg) {
    int i = blockIdx.x * blockDim.x + threadIdx.x;
    if (i < NUM_NODES) deg[i] = 0.0f;
}

__global__ void degree_kernel(const int* __restrict__ ei, float* __restrict__ deg) {
    int e = blockIdx.x * blockDim.x + threadIdx.x;
    if (e < E_CNT) {
        atomicAdd(&deg[ei[e]], 1.0f);
        atomicAdd(&deg[ei[E_CNT + e]], 1.0f);
    }
}

// W1T[n][k] = bf16(W1[k][n])
__global__ void prep_w1t_kernel(const float* __restrict__ W1, short* __restrict__ w1t) {
    int t = blockIdx.x * blockDim.x + threadIdx.x;   // 65536
    int n = t >> 8, k = t & 255;
    w1t[t] = f2bf(W1[k * 256 + n]);
}

// emb fp32 (800000x128) -> bf16 copy
__global__ void prep_emb_kernel(const float* __restrict__ emb, short* __restrict__ ebf) {
    long t = (long)blockIdx.x * blockDim.x + threadIdx.x;
    const float4* e4 = (const float4*)emb;
    float4 v0 = e4[t * 2], v1 = e4[t * 2 + 1];
    bf16x8 h;
    h[0] = f2bf(v0.x); h[1] = f2bf(v0.y); h[2] = f2bf(v0.z); h[3] = f2bf(v0.w);
    h[4] = f2bf(v1.x); h[5] = f2bf(v1.y); h[6] = f2bf(v1.z); h[7] = f2bf(v1.w);
    *(bf16x8*)&ebf[t * 8] = h;
}

// Persistent-block kernel. MODE 2: gather bf16 table; MODE 1: gather fp32 emb.
// pairS swizzle: 16B chunk c of row r holds logical chunk (c ^ (r&7)).
template <int MODE>
__launch_bounds__(TPB, 2)
__global__ void egis_main_kernel(
    const float* __restrict__ emb,
    const int*   __restrict__ eg,
    const int*   __restrict__ ei,
    const float* __restrict__ b1,
    const float* __restrict__ W2, const float* __restrict__ b2,
    const float* __restrict__ Ws1, const float* __restrict__ bs1,
    const float* __restrict__ Ws2, const float* __restrict__ bs2,
    const float* __restrict__ Wc1, const float* __restrict__ bc1,
    const float* __restrict__ Wc2, const float* __restrict__ bc2,
    const float* __restrict__ deg,
    const short* __restrict__ w1t,   // (256,256) bf16 [n][k]
    const short* __restrict__ ebf,   // (E,128) bf16
    float* __restrict__ out)
{
    __shared__ short pairS[2][32][256];   // 32 KB double-buffered; holds pair, then relu(h)
    __shared__ short w2tS[8][264];        // W2^T bf16 (row n, k-stride 264)
    __shared__ float compS[32][8];
    __shared__ float sfS[32][4];
    __shared__ int   gS[2][2][32];        // [buf][g0/g1][row]

    const int tid = threadIdx.x;
    const int wv = tid >> 6, lane = tid & 63;
    const int l32 = lane & 31, lh32 = lane >> 5;
    const int axr = l32 & 7;

    // ---- one-time setup: W1T fragments into registers, W2 into LDS ----
    bf16x8 bReg[16];
    {
        const bf16x8* B8 = (const bf16x8*)w1t;       // 32 chunks per n-row
        const int bBase = (wv * 32 + l32) * 32 + lh32;
        #pragma unroll
        for (int ks = 0; ks < 16; ++ks) bReg[ks] = B8[bBase + ks * 2];
    }
    const float b1v = b1[wv * 32 + l32];
    #pragma unroll
    for (int it = 0; it < 4; ++it) {
        int idx = it * TPB + tid;                    // k*8+n
        w2tS[idx & 7][idx >> 3] = f2bf(W2[idx]);
    }

    // ---- prologue ----
    int t = blockIdx.x;
    if (tid < 32) {
        int2 g = ((const int2*)eg)[t * 32 + tid];
        gS[0][0][tid] = g.x; gS[0][1][tid] = g.y;
    }
    __syncthreads();

    bf16x8 gReg[2];
    float4 gRegF[2][2];
    #pragma unroll
    for (int it = 0; it < 2; ++it) {
        int idx = it * TPB + tid;                    // row*32 + chunk
        int r = idx >> 5, rc = idx & 31;
        int gi = rc ^ (r & 7);
        int grow = (gi & 16) ? gS[0][1][r] : gS[0][0][r];
        if constexpr (MODE == 2) {
            gReg[it] = *(const bf16x8*)(ebf + (long)grow * 128 + (gi & 15) * 8);
        } else {
            const float4* s4 = (const float4*)(emb + (long)grow * 128 + (gi & 15) * 8);
            gRegF[it][0] = s4[0]; gRegF[it][1] = s4[1];
        }
    }
    int2 egReg = {0, 0};
    {
        int tn = (t + GRID < NT) ? t + GRID : NT - 1;
        if (tid < 32) egReg = ((const int2*)eg)[tn * 32 + tid];
    }

    int cur = 0;
    while (t < NT) {
        const int nxt = cur ^ 1;

        // write gathered pair(t) into pairS[cur]; publish next tile's indices
        #pragma unroll
        for (int it = 0; it < 2; ++it) {
            int idx = it * TPB + tid;
            int r = idx >> 5, rc = idx & 31;
            if constexpr (MODE == 2) {
                *(bf16x8*)&pairS[cur][r][rc * 8] = gReg[it];
            } else {
                float4 v0 = gRegF[it][0], v1 = gRegF[it][1];
                bf16x8 h;
                h[0] = f2bf(v0.x); h[1] = f2bf(v0.y); h[2] = f2bf(v0.z); h[3] = f2bf(v0.w);
                h[4] = f2bf(v1.x); h[5] = f2bf(v1.y); h[6] = f2bf(v1.z); h[7] = f2bf(v1.w);
                *(bf16x8*)&pairS[cur][r][rc * 8] = h;
            }
        }
        if (tid < 32) { gS[nxt][0][tid] = egReg.x; gS[nxt][1][tid] = egReg.y; }
        __syncthreads();   // pairS[cur] + gS[nxt] visible

        // issue gather(t+GRID) into gReg (consumed next iteration)
        #pragma unroll
        for (int it = 0; it < 2; ++it) {
            int idx = it * TPB + tid;
            int r = idx >> 5, rc = idx & 31;
            int gi = rc ^ (r & 7);
            int grow = (gi & 16) ? gS[nxt][1][r] : gS[nxt][0][r];
            if constexpr (MODE == 2) {
                gReg[it] = *(const bf16x8*)(ebf + (long)grow * 128 + (gi & 15) * 8);
            } else {
                const float4* s4 = (const float4*)(emb + (long)grow * 128 + (gi & 15) * 8);
                gRegF[it][0] = s4[0]; gRegF[it][1] = s4[1];
            }
        }
        // issue eg prefetch for t+2*GRID
        {
            int tn2 = (t + 2 * GRID < NT) ? t + 2 * GRID : NT - 1;
            if (tid < 32) egReg = ((const int2*)eg)[tn2 * 32 + tid];
        }
        // issue ss first-level random loads for tile t
        int eiv = 0;
        if (tid < 128) {
            int r = tid >> 2, j = tid & 3;
            int node = (j < 2) ? gS[cur][0][r] : gS[cur][1][r];
            eiv = ei[(j & 1) * E_CNT + node];
        }

        // ---- hidden = relu(pair @ W1 + b1): one 32x32 C-tile per wave ----
        f32x16 acc;
        #pragma unroll
        for (int i = 0; i < 16; ++i) acc[i] = b1v;
        {
            const short* aRow = &pairS[cur][l32][0];
            #pragma unroll
            for (int ks = 0; ks < 16; ++ks) {
                bf16x8 a = *(const bf16x8*)(aRow + (((ks * 2 + lh32) ^ axr)) * 8);
                acc = __builtin_amdgcn_mfma_f32_32x32x16_bf16(a, bReg[ks], acc, 0, 0, 0);
            }
        }
        __syncthreads();   // all waves done reading pairS[cur]

        // store relu(h) bf16 back into pairS[cur] (same swizzle)
        #pragma unroll
        for (int g = 0; g < 4; ++g) {
            #pragma unroll
            for (int i = 0; i < 4; ++i) {
                int row = g * 8 + lh32 * 4 + i;        // D: row=(reg&3)+8*(reg>>2)+4*(lane>>5)
                int col = wv * 32 + l32;               //    col=lane&31
                pairS[cur][row][col ^ ((row & 7) << 3)] = f2bf(fmaxf(acc[g * 4 + i], 0.f));
            }
        }

        // consume ei, issue deg loads
        float degv = 0.f;
        if (tid < 128) degv = deg[eiv];
        __syncthreads();   // h tile visible

        if (tid < 128) {
            int r = tid >> 2, j = tid & 3;
            sfS[r][j] = degv;
        }
        // ---- comp = relu(h @ W2 + b2): wave 0 only, cols 8..31 junk-masked ----
        if (wv == 0) {
            float c0 = (l32 < 8) ? b2[l32] : 0.f;
            f32x16 a2;
            #pragma unroll
            for (int i = 0; i < 16; ++i) a2[i] = c0;
            const short* hRow = &pairS[cur][l32][0];
            const short* w2row = &w2tS[l32 & 7][0];
            #pragma unroll
            for (int ks = 0; ks < 16; ++ks) {
                bf16x8 a = *(const bf16x8*)(hRow + (((ks * 2 + lh32) ^ axr)) * 8);
                bf16x8 b = *(const bf16x8*)(w2row + (ks * 2 + lh32) * 8);
                a2 = __builtin_amdgcn_mfma_f32_32x32x16_bf16(a, b, a2, 0, 0, 0);
            }
            if (l32 < 8) {
                #pragma unroll
                for (int g = 0; g < 4; ++g)
                    #pragma unroll
                    for (int i = 0; i < 4; ++i)
                        compS[g * 8 + lh32 * 4 + i][l32] = fmaxf(a2[g * 4 + i], 0.f);
            }
        }
        __syncthreads();   // compS + sfS visible

        // ---- tail: ss + head MLP, 16 threads per group-row ----
        {
            int r = tid >> 4, q = tid & 15;
            float s0 = sfS[r][0], s1 = sfS[r][1], s2 = sfS[r][2], s3 = sfS[r][3];
            float part = 0.f;
            #pragma unroll
            for (int i = 0; i < 4; ++i) {
                int u = q * 4 + i;
                float h = bs1[u] + s0 * Ws1[u] + s1 * Ws1[64 + u]
                                 + s2 * Ws1[128 + u] + s3 * Ws1[192 + u];
                part += fmaxf(h, 0.f) * Ws2[u];
            }
            part += __shfl_xor(part, 1);
            part += __shfl_xor(part, 2);
            part += __shfl_xor(part, 4);
            part += __shfl_xor(part, 8);
            float ssv = part + bs2[0];

            float as[8];
            #pragma unroll
            for (int a = 0; a < 8; ++a) as[a] = compS[r][a];
            float p2 = 0.f;
            #pragma unroll
            for (int i = 0; i < 8; ++i) {
                int u = q * 8 + i;
                float h = bc1[u];
                #pragma unroll
                for (int a = 0; a < 8; ++a) h += as[a] * Wc1[a * 128 + u];
                h += ssv * Wc1[1024 + u];
                p2 += fmaxf(h, 0.f) * Wc2[u];
            }
            p2 += __shfl_xor(p2, 1);
            p2 += __shfl_xor(p2, 2);
            p2 += __shfl_xor(p2, 4);
            p2 += __shfl_xor(p2, 8);
            if (q == 0) out[t * 32 + r] = 1.f / (1.f + expf(-(p2 + bc2[0])));
        }

        cur = nxt;
        t += GRID;
    }
}

extern "C" void kernel_launch(void* const* d_in, const int* in_sizes, int n_in,
                              void* d_out, int out_size, void* d_ws, size_t ws_size,
                              hipStream_t stream) {
    const float* emb = (const float*)d_in[0];
    const int*   eg  = (const int*)d_in[1];
    const int*   ei  = (const int*)d_in[2];
    const float* W1  = (const float*)d_in[3];
    const float* b1  = (const float*)d_in[4];
    const float* W2  = (const float*)d_in[5];
    const float* b2  = (const float*)d_in[6];
    const float* Ws1 = (const float*)d_in[7];
    const float* bs1 = (const float*)d_in[8];
    const float* Ws2 = (const float*)d_in[9];
    const float* bs2 = (const float*)d_in[10];
    const float* Wc1 = (const float*)d_in[11];
    const float* bc1 = (const float*)d_in[12];
    const float* Wc2 = (const float*)d_in[13];
    const float* bc2 = (const float*)d_in[14];
    float* out = (float*)d_out;

    // ws: deg | w1t bf16 | ebf bf16
    float* deg = (float*)d_ws;
    size_t degB = ((size_t)NUM_NODES * 4 + 255) & ~(size_t)255;
    short* w1t = (short*)((char*)d_ws + degB);
    size_t w1tB = 256 * 256 * sizeof(short);
    short* ebf = (short*)((char*)d_ws + degB + w1tB);
    size_t embB = (size_t)E_CNT * 128 * sizeof(short);

    int mode = (ws_size >= degB + w1tB + embB) ? 2 : 1;

    zero_deg_kernel<<<(NUM_NODES + 255) / 256, 256, 0, stream>>>(deg);
    degree_kernel<<<(E_CNT + 255) / 256, 256, 0, stream>>>(ei, deg);
    prep_w1t_kernel<<<65536 / 256, 256, 0, stream>>>(W1, w1t);
    if (mode == 2) {
        prep_emb_kernel<<<50000, 256, 0, stream>>>(emb, ebf);
        egis_main_kernel<2><<<GRID, TPB, 0, stream>>>(
            emb, eg, ei, b1, W2, b2, Ws1, bs1, Ws2, bs2, Wc1, bc1, Wc2, bc2,
            deg, w1t, ebf, out);
    } else {
        egis_main_kernel<1><<<GRID, TPB, 0, stream>>>(
            emb, eg, ei, b1, W2, b2, Ws1, bs1, Ws2, bs2, Wc1, bc1, Wc2, bc2,
            deg, w1t, (const short*)nullptr, out);
    }
}